// Round 1
// baseline (559.577 us; speedup 1.0000x reference)
//
#include <hip/hip_runtime.h>
#include <hip/hip_bf16.h>

#define ALPHA 0.2f

typedef __attribute__((ext_vector_type(8)))  __bf16 bf16x8;
typedef __attribute__((ext_vector_type(16))) float  f32x16;
typedef int          i32x4 __attribute__((ext_vector_type(4)));
typedef float        f32x4 __attribute__((ext_vector_type(4)));
typedef unsigned int u32x4 __attribute__((ext_vector_type(4)));

__device__ __forceinline__ unsigned short bf16bits(float v) {
    __bf16 b = (__bf16)v;
    unsigned short u;
    __builtin_memcpy(&u, &b, 2);
    return u;
}

// ---------- Kernel 1: h = x*W ; f1 = h@a1 ; f2 = h@a2 ; h_t = bf16 transpose ----------
__global__ __launch_bounds__(256) void gat_prep(
    const float* __restrict__ x, const float* __restrict__ W, const float* __restrict__ a,
    float* __restrict__ f1, float* __restrict__ f2, unsigned short* __restrict__ h_t,
    float* __restrict__ ws_acc)
{
    __shared__ unsigned short lh[128][72];   // [f][i], padded stride 144B (16B aligned)
    int t = threadIdx.x;
    int i0 = blockIdx.x * 64;
    if (blockIdx.x == 0 && t < 128) ws_acc[t] = 0.0f;

    int row = t >> 2, q = t & 3;             // 4 threads per row, 32 f each
    int i = i0 + row;
    const float4* xp  = (const float4*)(x + (size_t)i * 128 + q * 32);
    const float4* wp  = (const float4*)(W + (size_t)i * 128 + q * 32);
    const float4* a1p = (const float4*)(a + q * 32);
    const float4* a2p = (const float4*)(a + 128 + q * 32);
    float p1 = 0.f, p2 = 0.f;
    #pragma unroll
    for (int jj = 0; jj < 8; ++jj) {
        float4 xv = xp[jj], wv = wp[jj], a1v = a1p[jj], a2v = a2p[jj];
        float h0 = xv.x * wv.x, h1 = xv.y * wv.y, h2 = xv.z * wv.z, h3 = xv.w * wv.w;
        p1 += h0 * a1v.x + h1 * a1v.y + h2 * a1v.z + h3 * a1v.w;
        p2 += h0 * a2v.x + h1 * a2v.y + h2 * a2v.z + h3 * a2v.w;
        int fb = q * 32 + jj * 4;
        lh[fb + 0][row] = bf16bits(h0);
        lh[fb + 1][row] = bf16bits(h1);
        lh[fb + 2][row] = bf16bits(h2);
        lh[fb + 3][row] = bf16bits(h3);
    }
    p1 += __shfl_xor(p1, 1); p1 += __shfl_xor(p1, 2);
    p2 += __shfl_xor(p2, 1); p2 += __shfl_xor(p2, 2);
    if (q == 0) { f1[i] = p1; f2[i] = p2; }
    __syncthreads();

    int f = t >> 1, ih = (t & 1) * 32;       // each thread writes 32 bf16 (64B) of one f-row
    uint4* dst = (uint4*)(h_t + (size_t)f * 8192 + i0 + ih);
    const uint4* src = (const uint4*)(&lh[f][ih]);
    dst[0] = src[0]; dst[1] = src[1]; dst[2] = src[2]; dst[3] = src[3];
}

// ---------- Kernel 2: fused masked-softmax attention + adj@W2 row sums ----------
// grid: 256 blocks (32 rows each), 512 threads = 8 waves j-splitting the column space.
__global__ __launch_bounds__(512, 2) void gat_main(
    const int* __restrict__ adj, const float* __restrict__ x,
    const float* __restrict__ W2, const float* __restrict__ f1g,
    const float* __restrict__ f2g, const unsigned short* __restrict__ h_t,
    float* __restrict__ hp, float* __restrict__ ws_acc)
{
    __shared__ float lred[2 * 64 * 64];
    __shared__ float lden[2 * 64];
    __shared__ float lrs[2 * 64];

    int tid = threadIdx.x;
    int w = tid >> 6, l = tid & 63;
    int m = l & 31, half = l >> 5;
    int i0 = blockIdx.x * 32;

    float f1v = f1g[i0 + m];
    f32x16 acc[4] = {};
    float den = 0.f, rs = 0.f;

    const int* arow = adj + ((size_t)(i0 + m) << 13);
    const unsigned short* brow = h_t + ((size_t)m << 13);  // B n-index == l&31

    for (int it = 0; it < 64; ++it) {
        int jb = (w << 4) + (it << 7) + (half << 3);   // wave j-split, k-half offset
        i32x4 a0 = __builtin_nontemporal_load((const i32x4*)(arow + jb));
        i32x4 a1 = __builtin_nontemporal_load((const i32x4*)(arow + jb) + 1);
        f32x4 c0 = *(const f32x4*)(f2g + jb);
        f32x4 c1 = *(const f32x4*)(f2g + jb + 4);
        f32x4 w0 = *(const f32x4*)(W2 + jb);
        f32x4 w1 = *(const f32x4*)(W2 + jb + 4);
        union { u32x4 u; bf16x8 v; } b0, b1, b2, b3;
        b0.u = *(const u32x4*)(brow + jb);
        b1.u = *(const u32x4*)(brow + 262144 + jb);
        b2.u = *(const u32x4*)(brow + 524288 + jb);
        b3.u = *(const u32x4*)(brow + 786432 + jb);

        float tv[8] = {c0.x, c0.y, c0.z, c0.w, c1.x, c1.y, c1.z, c1.w};
        float wv[8] = {w0.x, w0.y, w0.z, w0.w, w1.x, w1.y, w1.z, w1.w};
        int   ad[8] = {a0.x, a0.y, a0.z, a0.w, a1.x, a1.y, a1.z, a1.w};
        bf16x8 afv;
        #pragma unroll
        for (int e = 0; e < 8; ++e) {
            float tt = f1v + tv[e];
            float lr = fmaxf(tt, ALPHA * tt);   // leakyrelu
            float ex = __expf(lr);
            float wg = (ad[e] != 0) ? ex : 0.0f;
            den += wg;
            rs  += (ad[e] != 0) ? wv[e] : 0.0f;
            afv[e] = (__bf16)wg;
        }
        acc[0] = __builtin_amdgcn_mfma_f32_32x32x16_bf16(afv, b0.v, acc[0], 0, 0, 0);
        acc[1] = __builtin_amdgcn_mfma_f32_32x32x16_bf16(afv, b1.v, acc[1], 0, 0, 0);
        acc[2] = __builtin_amdgcn_mfma_f32_32x32x16_bf16(afv, b2.v, acc[2], 0, 0, 0);
        acc[3] = __builtin_amdgcn_mfma_f32_32x32x16_bf16(afv, b3.v, acc[3], 0, 0, 0);
    }

    // combine the two k-halves of den / rs (lanes m and m+32 hold row m partials)
    den += __shfl_xor(den, 32);
    rs  += __shfl_xor(rs, 32);

    // 8-wave tree reduction through 2 LDS slots (33KB)
    float* av = (float*)acc;
    auto wrS = [&](int s) {
        #pragma unroll
        for (int j = 0; j < 64; ++j) lred[((s << 6) + j) * 64 + l] = av[j];
        lden[s * 64 + l] = den; lrs[s * 64 + l] = rs;
    };
    auto rdS = [&](int s) {
        #pragma unroll
        for (int j = 0; j < 64; ++j) av[j] += lred[((s << 6) + j) * 64 + l];
        den += lden[s * 64 + l]; rs += lrs[s * 64 + l];
    };
    if (w == 4 || w == 5) wrS(w - 4);
    __syncthreads();
    if (w == 0 || w == 1) rdS(w);
    __syncthreads();
    if (w == 6 || w == 7) wrS(w - 6);
    __syncthreads();
    if (w == 2 || w == 3) rdS(w - 2);
    __syncthreads();
    if (w == 2 || w == 3) wrS(w - 2);
    __syncthreads();
    if (w == 0 || w == 1) rdS(w);
    __syncthreads();
    if (w == 1) wrS(0);
    __syncthreads();
    if (w == 0) rdS(0);

    if (w == 0) {
        // per-reg reciprocal denominators (C/D row = (reg&3)+8*(reg>>2)+4*half)
        float rden[16];
        #pragma unroll
        for (int reg = 0; reg < 16; ++reg) {
            int rrow = (reg & 3) + 8 * (reg >> 2) + 4 * half;
            float dr = __shfl(den, rrow);
            rden[reg] = (dr != 0.f) ? 1.0f / dr : 0.f;
        }
        #pragma unroll
        for (int ft = 0; ft < 4; ++ft) {
            float* af = (float*)&acc[ft];
            #pragma unroll
            for (int reg = 0; reg < 16; ++reg) {
                int rrow = (reg & 3) + 8 * (reg >> 2) + 4 * half;
                __builtin_nontemporal_store(af[reg] * rden[reg],
                    hp + (size_t)(i0 + rrow) * 128 + ft * 32 + m);
            }
        }
        // out-path partial: sum_i r_i * x[i][:]  over this block's 32 rows
        float px = 0.f, py = 0.f;
        for (int mm = 0; mm < 32; ++mm) {
            float rm = __shfl(rs, mm);
            const float* xr = x + (size_t)(i0 + mm) * 128;
            px += rm * xr[l];
            py += rm * xr[l + 64];
        }
        atomicAdd(ws_acc + l, px);
        atomicAdd(ws_acc + l + 64, py);
    }
}

// ---------- Kernel 3: elu epilogue ----------
__global__ __launch_bounds__(128) void gat_finish(const float* __restrict__ ws_acc,
                                                  float* __restrict__ out)
{
    int t = threadIdx.x;
    float v = ws_acc[t];
    out[t] = (v > 0.f) ? v : (__expf(v) - 1.0f);
}

extern "C" void kernel_launch(void* const* d_in, const int* in_sizes, int n_in,
                              void* d_out, int out_size, void* d_ws, size_t ws_size,
                              hipStream_t stream) {
    const float* x   = (const float*)d_in[0];
    const int*   adj = (const int*)d_in[1];
    const float* W   = (const float*)d_in[2];
    const float* a   = (const float*)d_in[3];
    const float* W2  = (const float*)d_in[4];
    float* out = (float*)d_out;              // [0:128] elu out, [128:] h_prime [8192][128]

    float* wsf    = (float*)d_ws;
    float* ws_acc = wsf;                     // 128 floats
    float* f1     = wsf + 128;               // 8192 floats
    float* f2     = wsf + 128 + 8192;        // 8192 floats
    unsigned short* h_t = (unsigned short*)(wsf + 128 + 2 * 8192);  // bf16 [128][8192]

    gat_prep<<<128, 256, 0, stream>>>(x, W, a, f1, f2, h_t, ws_acc);
    gat_main<<<256, 512, 0, stream>>>(adj, x, W2, f1, f2, h_t, out + 128, ws_acc);
    gat_finish<<<1, 128, 0, stream>>>(ws_acc, out);
}

// Round 2
// 513.123 us; speedup vs baseline: 1.0905x; 1.0905x over previous
//
#include <hip/hip_runtime.h>
#include <hip/hip_bf16.h>

#define ALPHA 0.2f

typedef __attribute__((ext_vector_type(8)))  __bf16 bf16x8;
typedef __attribute__((ext_vector_type(16))) float  f32x16;
typedef int          i32x4 __attribute__((ext_vector_type(4)));
typedef float        f32x4 __attribute__((ext_vector_type(4)));
typedef unsigned int u32x4 __attribute__((ext_vector_type(4)));

__device__ __forceinline__ unsigned short bf16bits(float v) {
    __bf16 b = (__bf16)v;
    unsigned short u;
    __builtin_memcpy(&u, &b, 2);
    return u;
}

// ---------- Kernel 1: h = x*W ; f1 = h@a1 ; f2 = h@a2 ; h_t = bf16 transpose ----------
// 256 blocks x 256 threads, 32 rows/block (all CUs busy).
__global__ __launch_bounds__(256) void gat_prep(
    const float* __restrict__ x, const float* __restrict__ W, const float* __restrict__ a,
    float* __restrict__ f1, float* __restrict__ f2, unsigned short* __restrict__ h_t,
    float* __restrict__ ws_acc)
{
    __shared__ unsigned short lh[32][136];   // [i][f], padded stride 272B
    int t = threadIdx.x;
    int i0 = blockIdx.x * 32;
    if (blockIdx.x == 0 && t < 128) ws_acc[t] = 0.0f;

    int row = t >> 3, q = t & 7;             // 8 threads per row, 16 f each
    int i = i0 + row;
    const float4* xp  = (const float4*)(x + (size_t)i * 128 + q * 16);
    const float4* wp  = (const float4*)(W + (size_t)i * 128 + q * 16);
    const float4* a1p = (const float4*)(a + q * 16);
    const float4* a2p = (const float4*)(a + 128 + q * 16);
    float p1 = 0.f, p2 = 0.f;
    #pragma unroll
    for (int jj = 0; jj < 4; ++jj) {
        float4 xv = xp[jj], wv = wp[jj], a1v = a1p[jj], a2v = a2p[jj];
        float h0 = xv.x * wv.x, h1 = xv.y * wv.y, h2 = xv.z * wv.z, h3 = xv.w * wv.w;
        p1 += h0 * a1v.x + h1 * a1v.y + h2 * a1v.z + h3 * a1v.w;
        p2 += h0 * a2v.x + h1 * a2v.y + h2 * a2v.z + h3 * a2v.w;
        int fb = q * 16 + jj * 4;
        lh[row][fb + 0] = bf16bits(h0);
        lh[row][fb + 1] = bf16bits(h1);
        lh[row][fb + 2] = bf16bits(h2);
        lh[row][fb + 3] = bf16bits(h3);
    }
    p1 += __shfl_xor(p1, 1); p1 += __shfl_xor(p1, 2); p1 += __shfl_xor(p1, 4);
    p2 += __shfl_xor(p2, 1); p2 += __shfl_xor(p2, 2); p2 += __shfl_xor(p2, 4);
    if (q == 0) { f1[i] = p1; f2[i] = p2; }
    __syncthreads();

    // transpose out: thread t writes h_t[f][i0 + ih*16 .. +16] (32 B)
    int f = t >> 1, ih = (t & 1) * 16;
    unsigned int wbuf[8];
    #pragma unroll
    for (int k = 0; k < 8; ++k) {
        unsigned int lo = lh[ih + 2 * k][f];
        unsigned int hi = lh[ih + 2 * k + 1][f];
        wbuf[k] = lo | (hi << 16);
    }
    uint4* dst = (uint4*)(h_t + (size_t)f * 8192 + i0 + ih);
    dst[0] = make_uint4(wbuf[0], wbuf[1], wbuf[2], wbuf[3]);
    dst[1] = make_uint4(wbuf[4], wbuf[5], wbuf[6], wbuf[7]);
}

// ---------- Kernel 2: fused masked-softmax attention + adj@W2 row sums ----------
// grid: 256 blocks (32 rows each), 512 threads = 8 waves j-splitting the column space.
// Round-2 change: UNROLL=2 with batched load issue for memory-level parallelism.
__global__ __launch_bounds__(512, 2) void gat_main(
    const int* __restrict__ adj, const float* __restrict__ x,
    const float* __restrict__ W2, const float* __restrict__ f1g,
    const float* __restrict__ f2g, const unsigned short* __restrict__ h_t,
    float* __restrict__ hp, float* __restrict__ ws_acc)
{
    __shared__ float lred[2 * 64 * 64];
    __shared__ float lden[2 * 64];
    __shared__ float lrs[2 * 64];

    int tid = threadIdx.x;
    int w = tid >> 6, l = tid & 63;
    int m = l & 31, half = l >> 5;
    int i0 = blockIdx.x * 32;

    float f1v = f1g[i0 + m];
    f32x16 acc[4] = {};
    float den = 0.f, rs = 0.f;

    const int* arow = adj + ((size_t)(i0 + m) << 13);
    const unsigned short* brow = h_t + ((size_t)m << 13);

    for (int it = 0; it < 64; it += 2) {
        // ---- batched load issue: 2 iterations' worth of independent loads ----
        i32x4 a0[2], a1[2];
        f32x4 c0[2], c1[2], w0[2], w1[2];
        union { u32x4 u; bf16x8 v; } b0[2], b1[2], b2[2], b3[2];
        #pragma unroll
        for (int u = 0; u < 2; ++u) {
            int jb = (w << 4) + ((it + u) << 7) + (half << 3);
            a0[u] = __builtin_nontemporal_load((const i32x4*)(arow + jb));
            a1[u] = __builtin_nontemporal_load((const i32x4*)(arow + jb) + 1);
            c0[u] = *(const f32x4*)(f2g + jb);
            c1[u] = *(const f32x4*)(f2g + jb + 4);
            w0[u] = *(const f32x4*)(W2 + jb);
            w1[u] = *(const f32x4*)(W2 + jb + 4);
            b0[u].u = *(const u32x4*)(brow + jb);
            b1[u].u = *(const u32x4*)(brow + 262144 + jb);
            b2[u].u = *(const u32x4*)(brow + 524288 + jb);
            b3[u].u = *(const u32x4*)(brow + 786432 + jb);
        }
        // ---- consume ----
        #pragma unroll
        for (int u = 0; u < 2; ++u) {
            float tv[8] = {c0[u].x, c0[u].y, c0[u].z, c0[u].w,
                           c1[u].x, c1[u].y, c1[u].z, c1[u].w};
            float wv[8] = {w0[u].x, w0[u].y, w0[u].z, w0[u].w,
                           w1[u].x, w1[u].y, w1[u].z, w1[u].w};
            int   ad[8] = {a0[u].x, a0[u].y, a0[u].z, a0[u].w,
                           a1[u].x, a1[u].y, a1[u].z, a1[u].w};
            bf16x8 afv;
            #pragma unroll
            for (int e = 0; e < 8; ++e) {
                float tt = f1v + tv[e];
                float lr = fmaxf(tt, ALPHA * tt);   // leakyrelu
                float ex = __expf(lr);
                float wg = (ad[e] != 0) ? ex : 0.0f;
                den += wg;
                rs  += (ad[e] != 0) ? wv[e] : 0.0f;
                afv[e] = (__bf16)wg;
            }
            acc[0] = __builtin_amdgcn_mfma_f32_32x32x16_bf16(afv, b0[u].v, acc[0], 0, 0, 0);
            acc[1] = __builtin_amdgcn_mfma_f32_32x32x16_bf16(afv, b1[u].v, acc[1], 0, 0, 0);
            acc[2] = __builtin_amdgcn_mfma_f32_32x32x16_bf16(afv, b2[u].v, acc[2], 0, 0, 0);
            acc[3] = __builtin_amdgcn_mfma_f32_32x32x16_bf16(afv, b3[u].v, acc[3], 0, 0, 0);
        }
    }

    // combine the two k-halves of den / rs (lanes m and m+32 hold row m partials)
    den += __shfl_xor(den, 32);
    rs  += __shfl_xor(rs, 32);

    // 8-wave tree reduction through 2 LDS slots (33KB)
    float* av = (float*)acc;
    auto wrS = [&](int s) {
        #pragma unroll
        for (int j = 0; j < 64; ++j) lred[((s << 6) + j) * 64 + l] = av[j];
        lden[s * 64 + l] = den; lrs[s * 64 + l] = rs;
    };
    auto rdS = [&](int s) {
        #pragma unroll
        for (int j = 0; j < 64; ++j) av[j] += lred[((s << 6) + j) * 64 + l];
        den += lden[s * 64 + l]; rs += lrs[s * 64 + l];
    };
    if (w == 4 || w == 5) wrS(w - 4);
    __syncthreads();
    if (w == 0 || w == 1) rdS(w);
    __syncthreads();
    if (w == 6 || w == 7) wrS(w - 6);
    __syncthreads();
    if (w == 2 || w == 3) rdS(w - 2);
    __syncthreads();
    if (w == 2 || w == 3) wrS(w - 2);
    __syncthreads();
    if (w == 0 || w == 1) rdS(w);
    __syncthreads();
    if (w == 1) wrS(0);
    __syncthreads();
    if (w == 0) rdS(0);

    if (w == 0) {
        // per-reg reciprocal denominators (C/D row = (reg&3)+8*(reg>>2)+4*half)
        float rden[16];
        #pragma unroll
        for (int reg = 0; reg < 16; ++reg) {
            int rrow = (reg & 3) + 8 * (reg >> 2) + 4 * half;
            float dr = __shfl(den, rrow);
            rden[reg] = (dr != 0.f) ? 1.0f / dr : 0.f;
        }
        #pragma unroll
        for (int ft = 0; ft < 4; ++ft) {
            float* af = (float*)&acc[ft];
            #pragma unroll
            for (int reg = 0; reg < 16; ++reg) {
                int rrow = (reg & 3) + 8 * (reg >> 2) + 4 * half;
                __builtin_nontemporal_store(af[reg] * rden[reg],
                    hp + (size_t)(i0 + rrow) * 128 + ft * 32 + m);
            }
        }
        // out-path partial: sum_i r_i * x[i][:]  over this block's 32 rows
        float px = 0.f, py = 0.f;
        for (int mm = 0; mm < 32; ++mm) {
            float rm = __shfl(rs, mm);
            const float* xr = x + (size_t)(i0 + mm) * 128;
            px += rm * xr[l];
            py += rm * xr[l + 64];
        }
        atomicAdd(ws_acc + l, px);
        atomicAdd(ws_acc + l + 64, py);
    }
}

// ---------- Kernel 3: elu epilogue ----------
__global__ __launch_bounds__(128) void gat_finish(const float* __restrict__ ws_acc,
                                                  float* __restrict__ out)
{
    int t = threadIdx.x;
    float v = ws_acc[t];
    out[t] = (v > 0.f) ? v : (__expf(v) - 1.0f);
}

extern "C" void kernel_launch(void* const* d_in, const int* in_sizes, int n_in,
                              void* d_out, int out_size, void* d_ws, size_t ws_size,
                              hipStream_t stream) {
    const float* x   = (const float*)d_in[0];
    const int*   adj = (const int*)d_in[1];
    const float* W   = (const float*)d_in[2];
    const float* a   = (const float*)d_in[3];
    const float* W2  = (const float*)d_in[4];
    float* out = (float*)d_out;              // [0:128] elu out, [128:] h_prime [8192][128]

    float* wsf    = (float*)d_ws;
    float* ws_acc = wsf;                     // 128 floats
    float* f1     = wsf + 128;               // 8192 floats
    float* f2     = wsf + 128 + 8192;        // 8192 floats
    unsigned short* h_t = (unsigned short*)(wsf + 128 + 2 * 8192);  // bf16 [128][8192]

    gat_prep<<<256, 256, 0, stream>>>(x, W, a, f1, f2, h_t, ws_acc);
    gat_main<<<256, 512, 0, stream>>>(adj, x, W2, f1, f2, h_t, out + 128, ws_acc);
    gat_finish<<<1, 128, 0, stream>>>(ws_acc, out);
}

// Round 3
// 435.096 us; speedup vs baseline: 1.2861x; 1.1793x over previous
//
#include <hip/hip_runtime.h>
#include <hip/hip_bf16.h>

#define ALPHA 0.2f

typedef __attribute__((ext_vector_type(8)))  __bf16 bf16x8;
typedef __attribute__((ext_vector_type(16))) float  f32x16;
typedef int          i32x4 __attribute__((ext_vector_type(4)));
typedef float        f32x4 __attribute__((ext_vector_type(4)));
typedef unsigned int u32x4 __attribute__((ext_vector_type(4)));

static __device__ __forceinline__ unsigned short bf16bits(float v) {
    __bf16 b = (__bf16)v;
    unsigned short u;
    __builtin_memcpy(&u, &b, 2);
    return u;
}

// ---------- Kernel 1: h = x*W ; f1 = h@a1 ; f2 = h@a2 ; hB = MFMA-B-fragment-packed bf16 h ----------
// hB layout: fragment id = ks*4 + ft (ks = j/16, ft = f/32), each fragment 512 bf16:
//   element(lane s, e) = h[j = ks*16 + (s>>5)*8 + e][f = ft*32 + (s&31)]  at offset fragid*512 + s*8 + e
__global__ __launch_bounds__(256) void gat_prep(
    const float* __restrict__ x, const float* __restrict__ W, const float* __restrict__ a,
    float* __restrict__ f1, float* __restrict__ f2, unsigned short* __restrict__ hB,
    float* __restrict__ ws_acc)
{
    __shared__ unsigned short lh[32][136];   // [j-local][f]
    int t = threadIdx.x;
    int i0 = blockIdx.x * 32;
    if (blockIdx.x == 0 && t < 128) ws_acc[t] = 0.0f;

    int row = t >> 3, q = t & 7;             // 8 threads per row, 16 f each
    int i = i0 + row;
    const float4* xp  = (const float4*)(x + (size_t)i * 128 + q * 16);
    const float4* wp  = (const float4*)(W + (size_t)i * 128 + q * 16);
    const float4* a1p = (const float4*)(a + q * 16);
    const float4* a2p = (const float4*)(a + 128 + q * 16);
    float p1 = 0.f, p2 = 0.f;
    #pragma unroll
    for (int jj = 0; jj < 4; ++jj) {
        float4 xv = xp[jj], wv = wp[jj], a1v = a1p[jj], a2v = a2p[jj];
        float h0 = xv.x * wv.x, h1 = xv.y * wv.y, h2 = xv.z * wv.z, h3 = xv.w * wv.w;
        p1 += h0 * a1v.x + h1 * a1v.y + h2 * a1v.z + h3 * a1v.w;
        p2 += h0 * a2v.x + h1 * a2v.y + h2 * a2v.z + h3 * a2v.w;
        int fb = q * 16 + jj * 4;
        lh[row][fb + 0] = bf16bits(h0);
        lh[row][fb + 1] = bf16bits(h1);
        lh[row][fb + 2] = bf16bits(h2);
        lh[row][fb + 3] = bf16bits(h3);
    }
    p1 += __shfl_xor(p1, 1); p1 += __shfl_xor(p1, 2); p1 += __shfl_xor(p1, 4);
    p2 += __shfl_xor(p2, 1); p2 += __shfl_xor(p2, 2); p2 += __shfl_xor(p2, 4);
    if (q == 0) { f1[i] = p1; f2[i] = p2; }
    __syncthreads();

    // fragment-pack: this block covers ks = 2b, 2b+1
    int fl = t >> 5, s0 = t & 31;
    int ksl = fl >> 2, ft = fl & 3;
    size_t fragbase = ((size_t)(2 * blockIdx.x + ksl) * 4 + ft) * 512;
    #pragma unroll
    for (int hw = 0; hw < 2; ++hw) {
        int s = s0 + hw * 32;
        int jl = ksl * 16 + hw * 8;
        int f = ft * 32 + s0;
        unsigned int p[4];
        #pragma unroll
        for (int k = 0; k < 4; ++k) {
            unsigned int lo = lh[jl + 2 * k][f];
            unsigned int hi = lh[jl + 2 * k + 1][f];
            p[k] = lo | (hi << 16);
        }
        u32x4 v = {p[0], p[1], p[2], p[3]};
        *(u32x4*)(hB + fragbase + s * 8) = v;
    }
}

// ---------- Kernel 2: fused masked-softmax attention + adj@W2 row sums ----------
// 256 blocks x 512 threads (8 waves). Block owns 32 rows. 8 chunks of 1024 j.
// Phase A: coalesced adj/f2/W2 stream (wave owns 4 rows, lanes along j), wg -> LDS.
// Phase B: MFMA; A-frag from LDS, B-frag coalesced from fragment-packed hB.
__global__ __launch_bounds__(512, 2) void gat_main(
    const int* __restrict__ adj, const float* __restrict__ x,
    const float* __restrict__ W2, const float* __restrict__ f1g,
    const float* __restrict__ f2g, const unsigned short* __restrict__ hB,
    float* __restrict__ hp, float* __restrict__ ws_acc)
{
    __shared__ unsigned short wtile[32][1040];   // 66.5 KB, pad -> uniform banks
    __shared__ float den_s[32], rs_s[32];

    int tid = threadIdx.x;
    int wv = tid >> 6, l = tid & 63;
    int r0 = wv * 4;                 // phase-A row ownership
    int ft = wv & 3, jh = wv >> 2;   // phase-B tile ownership
    int i0 = blockIdx.x * 32;

    float f1r[4];
    #pragma unroll
    for (int ri = 0; ri < 4; ++ri) f1r[ri] = f1g[i0 + r0 + ri];

    f32x16 acc = {};
    float den4[4] = {0.f, 0.f, 0.f, 0.f}, rs4[4] = {0.f, 0.f, 0.f, 0.f};

    const int* abase = adj + (size_t)(i0 + r0) * 8192 + l * 4;

    i32x4 adjreg[4][4];
    f32x4 f2reg[4], w2reg[4];
    auto issue = [&](int c) {
        int j0 = c << 10;
        #pragma unroll
        for (int js = 0; js < 4; ++js) {
            int jo = j0 + js * 256 + l * 4;
            f2reg[js] = *(const f32x4*)(f2g + jo);
            w2reg[js] = *(const f32x4*)(W2 + jo);
            #pragma unroll
            for (int ri = 0; ri < 4; ++ri)
                adjreg[ri][js] = __builtin_nontemporal_load(
                    (const i32x4*)(abase + (size_t)ri * 8192 + j0 + js * 256));
        }
    };
    issue(0);

    for (int c = 0; c < 8; ++c) {
        // ---- Phase A: consume staged regs -> wg into LDS ----
        #pragma unroll
        for (int js = 0; js < 4; ++js) {
            f32x4 f2v = f2reg[js], w2v = w2reg[js];
            #pragma unroll
            for (int ri = 0; ri < 4; ++ri) {
                i32x4 ad = adjreg[ri][js];
                float wg[4];
                float rsum = 0.f, dsum = 0.f;
                #pragma unroll
                for (int e = 0; e < 4; ++e) {
                    float tt = f1r[ri] + f2v[e];
                    float lr = fmaxf(tt, ALPHA * tt);
                    float ex = __expf(lr);
                    float g = (ad[e] != 0) ? ex : 0.0f;
                    wg[e] = g;
                    dsum += g;
                    rsum += (ad[e] != 0) ? w2v[e] : 0.0f;
                }
                den4[ri] += dsum;
                rs4[ri] += rsum;
                unsigned int p0 = bf16bits(wg[0]) | ((unsigned int)bf16bits(wg[1]) << 16);
                unsigned int p1 = bf16bits(wg[2]) | ((unsigned int)bf16bits(wg[3]) << 16);
                *(uint2*)&wtile[r0 + ri][js * 256 + l * 4] = make_uint2(p0, p1);
            }
        }
        __syncthreads();
        if (c < 7) issue(c + 1);     // next chunk's HBM stream in flight through phase B

        // ---- Phase B: MFMA over this chunk ----
        const unsigned short* wrow = &wtile[l & 31][(jh << 9) + ((l >> 5) << 3)];
        const unsigned short* bptr = hB + (((size_t)(c * 64 + jh * 32) * 4 + ft) << 9) + (l << 3);
        #pragma unroll
        for (int ksl = 0; ksl < 32; ++ksl) {
            bf16x8 afrag = *(const bf16x8*)(wrow + ksl * 16);
            bf16x8 bfrag = *(const bf16x8*)(bptr + (size_t)ksl * 2048);
            acc = __builtin_amdgcn_mfma_f32_32x32x16_bf16(afrag, bfrag, acc, 0, 0, 0);
        }
        __syncthreads();
    }

    // ---- den / rs cross-lane reduction -> LDS ----
    #pragma unroll
    for (int ri = 0; ri < 4; ++ri) {
        float d = den4[ri], r = rs4[ri];
        #pragma unroll
        for (int off = 1; off < 64; off <<= 1) {
            d += __shfl_xor(d, off);
            r += __shfl_xor(r, off);
        }
        if (l == 0) { den_s[r0 + ri] = d; rs_s[r0 + ri] = r; }
    }

    // ---- 2-way acc reduction across j-halves (reuse wtile as float buffer) ----
    float* buf = (float*)&wtile[0][0];
    float* av = (float*)&acc;
    if (jh == 1) {
        #pragma unroll
        for (int j = 0; j < 16; ++j) buf[ft * 1024 + j * 64 + l] = av[j];
    }
    __syncthreads();
    if (jh == 0) {
        #pragma unroll
        for (int j = 0; j < 16; ++j) av[j] += buf[ft * 1024 + j * 64 + l];
        #pragma unroll
        for (int reg = 0; reg < 16; ++reg) {
            int rrow = (reg & 3) + 8 * (reg >> 2) + 4 * (l >> 5);
            float dr = den_s[rrow];
            float rv = (dr != 0.f) ? av[reg] / dr : 0.f;
            __builtin_nontemporal_store(rv,
                hp + (size_t)(i0 + rrow) * 128 + ft * 32 + (l & 31));
        }
    }

    // ---- out-path partial: sum_i rs[i] * x[i][:] over this block's rows ----
    if (wv == 0) {
        float px = 0.f, py = 0.f;
        #pragma unroll 4
        for (int mm = 0; mm < 32; ++mm) {
            float rm = rs_s[mm];
            const float* xr = x + (size_t)(i0 + mm) * 128;
            px += rm * xr[l];
            py += rm * xr[l + 64];
        }
        atomicAdd(ws_acc + l, px);
        atomicAdd(ws_acc + l + 64, py);
    }
}

// ---------- Kernel 3: elu epilogue ----------
__global__ __launch_bounds__(128) void gat_finish(const float* __restrict__ ws_acc,
                                                  float* __restrict__ out)
{
    int t = threadIdx.x;
    float v = ws_acc[t];
    out[t] = (v > 0.f) ? v : (__expf(v) - 1.0f);
}

extern "C" void kernel_launch(void* const* d_in, const int* in_sizes, int n_in,
                              void* d_out, int out_size, void* d_ws, size_t ws_size,
                              hipStream_t stream) {
    const float* x   = (const float*)d_in[0];
    const int*   adj = (const int*)d_in[1];
    const float* W   = (const float*)d_in[2];
    const float* a   = (const float*)d_in[3];
    const float* W2  = (const float*)d_in[4];
    float* out = (float*)d_out;              // [0:128] elu out, [128:] h_prime [8192][128]

    float* wsf    = (float*)d_ws;
    float* ws_acc = wsf;                     // 128 floats
    float* f1     = wsf + 128;               // 8192 floats
    float* f2     = wsf + 128 + 8192;        // 8192 floats
    unsigned short* hB = (unsigned short*)(wsf + 128 + 2 * 8192);  // bf16, 2 MB fragment-packed

    gat_prep<<<256, 256, 0, stream>>>(x, W, a, f1, f2, hB, ws_acc);
    gat_main<<<256, 512, 0, stream>>>(adj, x, W2, f1, f2, hB, out + 128, ws_acc);
    gat_finish<<<1, 128, 0, stream>>>(ws_acc, out);
}